// Round 2
// baseline (498.250 us; speedup 1.0000x reference)
//
#include <hip/hip_runtime.h>

#define D 1024
#define TPB 256           // 4 waves per block
#define NBLOCKS 2048      // 256 CU x 8 blocks/CU target; persistent grid-stride

typedef float f4 __attribute__((ext_vector_type(4)));

__device__ __forceinline__ void row_finish(
    f4 a0, f4 a1, f4 a2, f4 a3,
    f4 b0, f4 b1, f4 b2, f4 b3,
    int lane, float* __restrict__ out, int row) {
    float dot = 0.f, pp = 0.f, hh = 0.f;
#define ACC(A, B)                                                                    \
    dot = fmaf(A.x, B.x, dot); pp = fmaf(A.x, A.x, pp); hh = fmaf(B.x, B.x, hh);     \
    dot = fmaf(A.y, B.y, dot); pp = fmaf(A.y, A.y, pp); hh = fmaf(B.y, B.y, hh);     \
    dot = fmaf(A.z, B.z, dot); pp = fmaf(A.z, A.z, pp); hh = fmaf(B.z, B.z, hh);     \
    dot = fmaf(A.w, B.w, dot); pp = fmaf(A.w, A.w, pp); hh = fmaf(B.w, B.w, hh);
    ACC(a0, b0) ACC(a1, b1) ACC(a2, b2) ACC(a3, b3)
#undef ACC

    // Wave-64 butterfly-ish reduce; 3 independent chains interleave on the DS pipe.
#pragma unroll
    for (int off = 32; off > 0; off >>= 1) {
        dot += __shfl_down(dot, off, 64);
        pp  += __shfl_down(pp,  off, 64);
        hh  += __shfl_down(hh,  off, 64);
    }
    if (lane == 0) {
        const float eps = 1e-12f;
        float denom = fmaxf(sqrtf(pp), eps) * fmaxf(sqrtf(hh), eps);
        out[row] = dot / denom;
    }
}

__global__ __launch_bounds__(TPB, 4) void CosineSimilarity_76785425318088_kernel(
    const float* __restrict__ premise,
    const float* __restrict__ hypothesis,
    float* __restrict__ out,
    int n_rows) {
    const int lane = threadIdx.x & 63;
    const int wave = threadIdx.x >> 6;     // wave = 64 lanes on CDNA
    const int wpb  = TPB >> 6;
    const int S    = gridDim.x * wpb;      // total waves = row stride
    const int row0 = blockIdx.x * wpb + wave;
    if (row0 >= n_rows) return;
    // exact per-wave trip count -> branch-free main loop, precise vmcnt waits
    const int my_rows = (n_rows - 1 - row0) / S + 1;

    const f4* __restrict__ pbase = reinterpret_cast<const f4*>(premise);
    const f4* __restrict__ hbase = reinterpret_cast<const f4*>(hypothesis);
    const int QF = D / 4;                  // 256 f4 per row; 64 lanes -> 4 chunks

    // ---- prologue: load first row (plain loads; NT hint removed) ----
    f4 a0, a1, a2, a3, b0, b1, b2, b3;
    {
        const f4* pr = pbase + (size_t)row0 * QF + lane;
        const f4* hr = hbase + (size_t)row0 * QF + lane;
        a0 = pr[0];   b0 = hr[0];
        a1 = pr[64];  b1 = hr[64];
        a2 = pr[128]; b2 = hr[128];
        a3 = pr[192]; b3 = hr[192];
    }

    int row = row0;
    for (int i = 1; i < my_rows; ++i) {
        const int nrow = row0 + i * S;
        // Unconditional prefetch of next row: compiler can keep exactly 8
        // loads outstanding and wait vmcnt(8) before the FMAs below.
        const f4* pr = pbase + (size_t)nrow * QF + lane;
        const f4* hr = hbase + (size_t)nrow * QF + lane;
        f4 na0 = pr[0],   nb0 = hr[0];
        f4 na1 = pr[64],  nb1 = hr[64];
        f4 na2 = pr[128], nb2 = hr[128];
        f4 na3 = pr[192], nb3 = hr[192];

        row_finish(a0, a1, a2, a3, b0, b1, b2, b3, lane, out, row);

        row = nrow;
        a0 = na0; a1 = na1; a2 = na2; a3 = na3;   // register rename
        b0 = nb0; b1 = nb1; b2 = nb2; b3 = nb3;
    }

    row_finish(a0, a1, a2, a3, b0, b1, b2, b3, lane, out, row);
}

extern "C" void kernel_launch(void* const* d_in, const int* in_sizes, int n_in,
                              void* d_out, int out_size, void* d_ws, size_t ws_size,
                              hipStream_t stream) {
    const float* premise    = (const float*)d_in[0];
    const float* hypothesis = (const float*)d_in[1];
    float* out = (float*)d_out;
    const int n_rows = out_size;  // 65536

    const int wpb = TPB >> 6;
    int blocks = NBLOCKS;
    int max_useful = (n_rows + wpb - 1) / wpb;
    if (blocks > max_useful) blocks = max_useful;

    CosineSimilarity_76785425318088_kernel<<<blocks, TPB, 0, stream>>>(
        premise, hypothesis, out, n_rows);
}

// Round 3
// 473.260 us; speedup vs baseline: 1.0528x; 1.0528x over previous
//
#include <hip/hip_runtime.h>

#define D 1024
#define TPB 256           // 4 waves per block
#define NBLOCKS 2048      // 256 CU x 8 blocks/CU target; persistent grid-stride

typedef float f4 __attribute__((ext_vector_type(4)));

__device__ __forceinline__ void row_finish(
    f4 a0, f4 a1, f4 a2, f4 a3,
    f4 b0, f4 b1, f4 b2, f4 b3,
    int lane, float* __restrict__ out, int row) {
    float dot = 0.f, pp = 0.f, hh = 0.f;
#define ACC(A, B)                                                                    \
    dot = fmaf(A.x, B.x, dot); pp = fmaf(A.x, A.x, pp); hh = fmaf(B.x, B.x, hh);     \
    dot = fmaf(A.y, B.y, dot); pp = fmaf(A.y, A.y, pp); hh = fmaf(B.y, B.y, hh);     \
    dot = fmaf(A.z, B.z, dot); pp = fmaf(A.z, A.z, pp); hh = fmaf(B.z, B.z, hh);     \
    dot = fmaf(A.w, B.w, dot); pp = fmaf(A.w, A.w, pp); hh = fmaf(B.w, B.w, hh);
    ACC(a0, b0) ACC(a1, b1) ACC(a2, b2) ACC(a3, b3)
#undef ACC

    // Wave-64 reduce; 3 independent chains interleave on the DS pipe.
#pragma unroll
    for (int off = 32; off > 0; off >>= 1) {
        dot += __shfl_down(dot, off, 64);
        pp  += __shfl_down(pp,  off, 64);
        hh  += __shfl_down(hh,  off, 64);
    }
    if (lane == 0) {
        const float eps = 1e-12f;
        float denom = fmaxf(sqrtf(pp), eps) * fmaxf(sqrtf(hh), eps);
        __builtin_nontemporal_store(dot / denom, out + row);
    }
}

__global__ __launch_bounds__(TPB, 4) void CosineSimilarity_76785425318088_kernel(
    const float* __restrict__ premise,
    const float* __restrict__ hypothesis,
    float* __restrict__ out,
    int n_rows) {
    const int lane = threadIdx.x & 63;
    const int wave = threadIdx.x >> 6;     // wave = 64 lanes on CDNA
    const int wpb  = TPB >> 6;
    const int S    = gridDim.x * wpb;      // total waves = row stride
    const int row0 = blockIdx.x * wpb + wave;
    if (row0 >= n_rows) return;
    // exact per-wave trip count -> branch-free main loop, precise vmcnt waits
    const int my_rows = (n_rows - 1 - row0) / S + 1;

    const f4* __restrict__ pbase = reinterpret_cast<const f4*>(premise);
    const f4* __restrict__ hbase = reinterpret_cast<const f4*>(hypothesis);
    const int QF = D / 4;                  // 256 f4 per row; 64 lanes -> 4 chunks

    // ---- prologue: load first row (nontemporal: pure stream, no reuse; avoids
    // evicting the poison-fill's dirty L2/L3 lines on the critical path) ----
    f4 a0, a1, a2, a3, b0, b1, b2, b3;
    {
        const f4* pr = pbase + (size_t)row0 * QF + lane;
        const f4* hr = hbase + (size_t)row0 * QF + lane;
        a0 = __builtin_nontemporal_load(pr);       b0 = __builtin_nontemporal_load(hr);
        a1 = __builtin_nontemporal_load(pr + 64);  b1 = __builtin_nontemporal_load(hr + 64);
        a2 = __builtin_nontemporal_load(pr + 128); b2 = __builtin_nontemporal_load(hr + 128);
        a3 = __builtin_nontemporal_load(pr + 192); b3 = __builtin_nontemporal_load(hr + 192);
    }

    int row = row0;
    for (int i = 1; i < my_rows; ++i) {
        const int nrow = row0 + i * S;
        // Unconditional prefetch of next row: 8 loads outstanding during the
        // current row's FMA/reduce tail.
        const f4* pr = pbase + (size_t)nrow * QF + lane;
        const f4* hr = hbase + (size_t)nrow * QF + lane;
        f4 na0 = __builtin_nontemporal_load(pr);
        f4 nb0 = __builtin_nontemporal_load(hr);
        f4 na1 = __builtin_nontemporal_load(pr + 64);
        f4 nb1 = __builtin_nontemporal_load(hr + 64);
        f4 na2 = __builtin_nontemporal_load(pr + 128);
        f4 nb2 = __builtin_nontemporal_load(hr + 128);
        f4 na3 = __builtin_nontemporal_load(pr + 192);
        f4 nb3 = __builtin_nontemporal_load(hr + 192);

        row_finish(a0, a1, a2, a3, b0, b1, b2, b3, lane, out, row);

        row = nrow;
        a0 = na0; a1 = na1; a2 = na2; a3 = na3;   // register rename
        b0 = nb0; b1 = nb1; b2 = nb2; b3 = nb3;
    }

    row_finish(a0, a1, a2, a3, b0, b1, b2, b3, lane, out, row);
}

extern "C" void kernel_launch(void* const* d_in, const int* in_sizes, int n_in,
                              void* d_out, int out_size, void* d_ws, size_t ws_size,
                              hipStream_t stream) {
    const float* premise    = (const float*)d_in[0];
    const float* hypothesis = (const float*)d_in[1];
    float* out = (float*)d_out;
    const int n_rows = out_size;  // 65536

    const int wpb = TPB >> 6;
    int blocks = NBLOCKS;
    int max_useful = (n_rows + wpb - 1) / wpb;
    if (blocks > max_useful) blocks = max_useful;

    CosineSimilarity_76785425318088_kernel<<<blocks, TPB, 0, stream>>>(
        premise, hypothesis, out, n_rows);
}

// Round 4
// 472.747 us; speedup vs baseline: 1.0539x; 1.0011x over previous
//
#include <hip/hip_runtime.h>

#define D 1024
#define TPB 256           // 4 waves per block
#define NBLOCKS 2048      // 8 blocks/CU x 256 CU -> entire grid resident at 8 waves/SIMD

typedef float f4 __attribute__((ext_vector_type(4)));

// Simple high-occupancy streaming kernel (T14 lesson: on memory-bound streaming
// ops, TLP at high occupancy beats manual register pipelining). 32 data VGPRs,
// launch_bounds(256,8) caps allocation at 64 VGPR -> 8 waves/SIMD.
__global__ __launch_bounds__(TPB, 8) void CosineSimilarity_76785425318088_kernel(
    const float* __restrict__ premise,
    const float* __restrict__ hypothesis,
    float* __restrict__ out,
    int n_rows) {
    const int lane = threadIdx.x & 63;
    const int wave = threadIdx.x >> 6;     // wave = 64 lanes on CDNA
    const int wpb  = TPB >> 6;
    const int S    = gridDim.x * wpb;      // total waves = row stride
    const int row0 = blockIdx.x * wpb + wave;
    if (row0 >= n_rows) return;
    const int QF = D / 4;                  // 256 f4 per row; 64 lanes -> 4 chunks

    // Per-lane pointers; chunk offsets +64/+128/+192 f4 = +1024/2048/3072 B fold
    // into the load's 13-bit signed immediate. Per-iteration advance is one add.
    const f4* pr = reinterpret_cast<const f4*>(premise)    + (size_t)row0 * QF + lane;
    const f4* hr = reinterpret_cast<const f4*>(hypothesis) + (size_t)row0 * QF + lane;
    const size_t step = (size_t)S * QF;    // 32 MiB in f4 units

    for (int row = row0; row < n_rows; row += S) {
        // One 16 KB/wave burst (8 x dwordx4 x 64 lanes); nontemporal: pure
        // stream with zero reuse, and skips evicting the harness fill's dirty
        // L2/L3 lines (measured -25 us vs plain loads, r2->r3).
        f4 a0 = __builtin_nontemporal_load(pr);
        f4 b0 = __builtin_nontemporal_load(hr);
        f4 a1 = __builtin_nontemporal_load(pr + 64);
        f4 b1 = __builtin_nontemporal_load(hr + 64);
        f4 a2 = __builtin_nontemporal_load(pr + 128);
        f4 b2 = __builtin_nontemporal_load(hr + 128);
        f4 a3 = __builtin_nontemporal_load(pr + 192);
        f4 b3 = __builtin_nontemporal_load(hr + 192);

        float dot = 0.f, pp = 0.f, hh = 0.f;
#define ACC(A, B)                                                                    \
        dot = fmaf(A.x, B.x, dot); pp = fmaf(A.x, A.x, pp); hh = fmaf(B.x, B.x, hh); \
        dot = fmaf(A.y, B.y, dot); pp = fmaf(A.y, A.y, pp); hh = fmaf(B.y, B.y, hh); \
        dot = fmaf(A.z, B.z, dot); pp = fmaf(A.z, A.z, pp); hh = fmaf(B.z, B.z, hh); \
        dot = fmaf(A.w, B.w, dot); pp = fmaf(A.w, A.w, pp); hh = fmaf(B.w, B.w, hh);
        ACC(a0, b0) ACC(a1, b1) ACC(a2, b2) ACC(a3, b3)
#undef ACC

        // Wave-64 reduce; 3 independent chains interleave on the DS pipe.
#pragma unroll
        for (int off = 32; off > 0; off >>= 1) {
            dot += __shfl_down(dot, off, 64);
            pp  += __shfl_down(pp,  off, 64);
            hh  += __shfl_down(hh,  off, 64);
        }
        if (lane == 0) {
            const float eps = 1e-12f;
            float denom = fmaxf(sqrtf(pp), eps) * fmaxf(sqrtf(hh), eps);
            __builtin_nontemporal_store(dot / denom, out + row);
        }

        pr += step; hr += step;
    }
}

extern "C" void kernel_launch(void* const* d_in, const int* in_sizes, int n_in,
                              void* d_out, int out_size, void* d_ws, size_t ws_size,
                              hipStream_t stream) {
    const float* premise    = (const float*)d_in[0];
    const float* hypothesis = (const float*)d_in[1];
    float* out = (float*)d_out;
    const int n_rows = out_size;  // 65536

    const int wpb = TPB >> 6;
    int blocks = NBLOCKS;
    int max_useful = (n_rows + wpb - 1) / wpb;
    if (blocks > max_useful) blocks = max_useful;

    CosineSimilarity_76785425318088_kernel<<<blocks, TPB, 0, stream>>>(
        premise, hypothesis, out, n_rows);
}